// Round 13
// baseline (254.484 us; speedup 1.0000x reference)
//
#include <hip/hip_runtime.h>

#define NPTS 65536
#define INC  256
#define MID  64
#define KNB  16
#define WSTR 72   // padded LDS row stride (shorts)

// fragment-buffer offsets in shorts (workspace, written by k_prep)
#define WIN_S   0        // w_in   2048 entries
#define WQ_S    16384    // WQ1 = W1s @ w_q (fully folded Q)   512
#define WK_S    20480    // w_k     512
#define WV_S    24576    // w_v     512
#define GA1_S   28672    // ga_w1 * s1 (bn1-folded)   512
#define GA2_S   32768    // ga_w2 * s2 * log2(e)      512
#define WOUT_S  36864    // w_out  2048
#define NFRAG_ENT 6656
#define BQ1F_S  53248    // combined Q bias, 64 floats (short offset, 4B-aligned)

#define LOG2E 1.44269504088896340736f

typedef __attribute__((ext_vector_type(8))) short short8;
typedef __attribute__((ext_vector_type(4))) float f32x4;

#define MFMA(a, b, c) __builtin_amdgcn_mfma_f32_16x16x32_bf16((a), (b), (c), 0, 0, 0)
#define WBAR() __builtin_amdgcn_wave_barrier()

__device__ inline float bf2f(unsigned short s) {
    unsigned int u = ((unsigned int)s) << 16;
    return __builtin_bit_cast(float, u);
}
// HW packed f32->bf16 (RNE), 1 VALU op for 2 values
__device__ inline unsigned int pk_bf16(float lo, float hi) {
    unsigned int r;
    asm("v_cvt_pk_bf16_f32 %0, %1, %2" : "=v"(r) : "v"(lo), "v"(hi));
    return r;
}
__device__ inline short f2bf(float f) { return (short)pk_bf16(f, f); }
// native 2^x (v_exp_f32 IS exp2 on gfx950)
__device__ inline float exp2fast(float x) {
    float r;
    asm("v_exp_f32 %0, %1" : "=v"(r) : "v"(x));
    return r;
}

__device__ inline short8 cvtf8(f32x4 a, f32x4 b) {
    union { unsigned int u[4]; short8 s; } r;
    r.u[0] = pk_bf16(a[0], a[1]); r.u[1] = pk_bf16(a[2], a[3]);
    r.u[2] = pk_bf16(b[0], b[1]); r.u[3] = pk_bf16(b[2], b[3]);
    return r.s;
}
__device__ inline short8 load_cvt8(const float* __restrict__ p) {
    const f32x4* v = (const f32x4*)p;
    return cvtf8(v[0], v[1]);
}
__device__ inline short8 load_cvt8s(const float* __restrict__ p, float scale) {
    const f32x4* v = (const f32x4*)p;
    f32x4 a = v[0], b = v[1];
    #pragma unroll
    for (int i = 0; i < 4; i++) { a[i] *= scale; b[i] *= scale; }
    return cvtf8(a, b);
}

// ---------------------------------------------------------------------------
// Kernel 0: weights -> bf16 MFMA B-fragment order. (unchanged, verified)
// ---------------------------------------------------------------------------
__global__ __launch_bounds__(256) void k_prep(
    const float* __restrict__ w_in, const float* __restrict__ w_q,
    const float* __restrict__ w_k, const float* __restrict__ w_v,
    const float* __restrict__ ga_w1, const float* __restrict__ ga_w2,
    const float* __restrict__ w_out, const float* __restrict__ b_q,
    const float* __restrict__ ga_g1, const float* __restrict__ ga_v1,
    const float* __restrict__ ga_b1, const float* __restrict__ ga_be1,
    const float* __restrict__ ga_m1,
    const float* __restrict__ ga_g2, const float* __restrict__ ga_v2,
    short* __restrict__ wbuf)
{
    int gid = blockIdx.x * 256 + threadIdx.x;
    if (gid >= NFRAG_ENT + 64) return;
    if (gid < 2048) {                               // w_in [64][256]
        int e = gid, f = e >> 6, ln = e & 63;
        int nt = f & 3, ks = f >> 2;
        int row = nt * 16 + (ln & 15), col = ks * 32 + (ln >> 4) * 8;
        *(short8*)&wbuf[(size_t)gid * 8] = load_cvt8(w_in + (size_t)row * INC + col);
    } else if (gid < 4608) {                        // five [64][64] matrices
        int seg = (gid - 2048) >> 9;
        int e = (gid - 2048) & 511;
        int f = e >> 6, ln = e & 63;
        int nt = f & 3, ks = f >> 2;
        int row = nt * 16 + (ln & 15), col = ks * 32 + (ln >> 4) * 8;
        if (seg == 0) {
            // WQ1[row][col+o] = s1[row] * sum_c ga_w1[row][c] * w_q[c][col+o]
            float s1r = ga_g1[row] * rsqrtf(ga_v1[row] + 1e-5f);
            float accv[8];
            #pragma unroll
            for (int o = 0; o < 8; o++) accv[o] = 0.f;
            for (int c = 0; c < 64; c++) {
                float a = ga_w1[(size_t)row * MID + c] * s1r;
                #pragma unroll
                for (int o = 0; o < 8; o++)
                    accv[o] += a * w_q[(size_t)c * MID + col + o];
            }
            f32x4 lo = {accv[0], accv[1], accv[2], accv[3]};
            f32x4 hi = {accv[4], accv[5], accv[6], accv[7]};
            *(short8*)&wbuf[(size_t)gid * 8] = cvtf8(lo, hi);
        } else {
            const float* m = seg == 1 ? w_k : seg == 2 ? w_v
                           : seg == 3 ? ga_w1 : ga_w2;
            float scale = 1.f;
            if (seg == 3)      scale = ga_g1[row] * rsqrtf(ga_v1[row] + 1e-5f);
            else if (seg == 4) scale = ga_g2[row] * rsqrtf(ga_v2[row] + 1e-5f) * LOG2E;
            *(short8*)&wbuf[(size_t)gid * 8] = load_cvt8s(m + (size_t)row * MID + col, scale);
        }
    } else if (gid < NFRAG_ENT) {                   // w_out [256][64]
        int e = gid - 4608, f = e >> 6, ln = e & 63;
        int nt = f >> 1, ks = f & 1;
        int row = nt * 16 + (ln & 15), col = ks * 32 + (ln >> 4) * 8;
        *(short8*)&wbuf[(size_t)gid * 8] = load_cvt8(w_out + (size_t)row * MID + col);
    } else {                                        // combined Q bias (64 floats)
        int ch = gid - NFRAG_ENT;
        float s1r = ga_g1[ch] * rsqrtf(ga_v1[ch] + 1e-5f);
        float acc = 0.f;
        for (int c = 0; c < 64; c++) acc += ga_w1[(size_t)ch * MID + c] * b_q[c];
        float beta1 = (ga_b1[ch] - ga_m1[ch]) * s1r + ga_be1[ch];
        ((float*)(wbuf + BQ1F_S))[ch] = s1r * acc - beta1;
    }
}

// ---------------------------------------------------------------------------
// Kernel 1: per 16-row tile compute, SPLIT 2 WAVES PER TILE for 2x occupancy.
//   xx  = feats @ w_in^T
//   Q1f = xx @ WQ1^T + bQ1                    [bf16 out]
//   K1  = (xx @ w_k^T + b_k + pe) @ W1s^T     -> lo half of kv
//   vp  =  xx @ w_v^T + b_v + pe              -> hi half of kv
// Each wave computes the 2-nt half (channels half*32..+31) of every stage;
// full-row A-fragments are exchanged through XLa/XLb + block syncs.
// Total waves 4096 -> 8192 (8/SIMD vs 4): hides B-frag L2 latency + MFMA
// chains that were exposed at 4 waves/SIMD.
// block = 256 (4 waves = 2 tiles); grid = 2048. LDS 9.7 KB.
// ---------------------------------------------------------------------------
__global__ __launch_bounds__(256) void k_qkv(
    const float* __restrict__ feats, const short* __restrict__ wfrag,
    const float* __restrict__ pos,
    const float* __restrict__ b_k, const float* __restrict__ b_v,
    const float* __restrict__ pe_w1, const float* __restrict__ pe_b1,
    const float* __restrict__ pe_g1, const float* __restrict__ pe_be1,
    const float* __restrict__ pe_m1, const float* __restrict__ pe_v1,
    const float* __restrict__ pe_w2, const float* __restrict__ pe_b2,
    const float* __restrict__ pe_g2, const float* __restrict__ pe_be2,
    const float* __restrict__ pe_m2, const float* __restrict__ pe_v2,
    short* __restrict__ q1f_out, unsigned* __restrict__ kv_out)
{
    __shared__ __align__(16) short XLa[2][16 * WSTR];  // xx tiles
    __shared__ __align__(16) short XLb[2][16 * WSTR];  // k' tiles
    __shared__ float PS[2][16 * 4];                    // PE1 per row
    const int tid = threadIdx.x;
    const int wave = tid >> 6, lane = tid & 63;
    const int l15 = lane & 15, quad = lane >> 4;
    const int tile = wave >> 1;            // 0..1
    const int half = wave & 1;             // 0..1 -> nt in {2*half, 2*half+1}
    const int nt0 = half * 2;
    const int rb = (blockIdx.x * 2 + tile) * 16;

    // PE1 for the tile's 16 rows (one wave of the pair writes; sync below)
    if (half == 0 && lane < 16) {
        float s0 = pe_g1[0] * rsqrtf(pe_v1[0] + 1e-5f);
        float s1 = pe_g1[1] * rsqrtf(pe_v1[1] + 1e-5f);
        float sc = pe_g1[2] * rsqrtf(pe_v1[2] + 1e-5f);
        float px = pos[(size_t)(rb + lane) * 3 + 0];
        float py = pos[(size_t)(rb + lane) * 3 + 1];
        float pz = pos[(size_t)(rb + lane) * 3 + 2];
        PS[tile][lane * 4 + 0] =
            fmaxf((px * pe_w1[0] + py * pe_w1[1] + pz * pe_w1[2] + pe_b1[0] - pe_m1[0]) * s0 + pe_be1[0], 0.f);
        PS[tile][lane * 4 + 1] =
            fmaxf((px * pe_w1[3] + py * pe_w1[4] + pz * pe_w1[5] + pe_b1[1] - pe_m1[1]) * s1 + pe_be1[1], 0.f);
        PS[tile][lane * 4 + 2] =
            fmaxf((px * pe_w1[6] + py * pe_w1[7] + pz * pe_w1[8] + pe_b1[2] - pe_m1[2]) * sc + pe_be1[2], 0.f);
    }

    // per-lane channel params for this wave's 2 nt (ch = (nt0+i)*16 + l15)
    const float* bq1f = (const float*)(wfrag + BQ1F_S);
    float w2c0[2], w2c1[2], w2c2[2], s2c[2], sh2c[2], bq1c[2], bkc[2], bvc[2];
    #pragma unroll
    for (int i = 0; i < 2; i++) {
        int ch = (nt0 + i) * 16 + l15;
        w2c0[i] = pe_w2[ch * 3 + 0]; w2c1[i] = pe_w2[ch * 3 + 1]; w2c2[i] = pe_w2[ch * 3 + 2];
        float s2 = pe_g2[ch] * rsqrtf(pe_v2[ch] + 1e-5f);
        s2c[i] = s2;
        sh2c[i] = (pe_b2[ch] - pe_m2[ch]) * s2 + pe_be2[ch];
        bq1c[i] = bq1f[ch];
        bkc[i] = b_k[ch]; bvc[i] = b_v[ch];
    }

    // xx half: channels (nt0..nt0+1)*16
    f32x4 acc[2];
    #pragma unroll
    for (int i = 0; i < 2; i++) acc[i] = (f32x4){0.f, 0.f, 0.f, 0.f};
    const float* arow = feats + (size_t)(rb + l15) * INC + quad * 8;
    #pragma unroll
    for (int ks = 0; ks < 8; ks++) {
        short8 a = load_cvt8(arow + ks * 32);
        #pragma unroll
        for (int i = 0; i < 2; i++) {
            short8 b = *(const short8*)&wfrag[WIN_S + (size_t)((ks * 4 + nt0 + i) * 64 + lane) * 8];
            acc[i] = MFMA(a, b, acc[i]);
        }
    }
    #pragma unroll
    for (int i = 0; i < 2; i++) {
        unsigned int p01 = pk_bf16(acc[i][0], acc[i][1]);
        unsigned int p23 = pk_bf16(acc[i][2], acc[i][3]);
        int cb = (nt0 + i) * 16 + l15;
        XLa[tile][(quad * 4 + 0) * WSTR + cb] = (short)p01;
        XLa[tile][(quad * 4 + 1) * WSTR + cb] = (short)(p01 >> 16);
        XLa[tile][(quad * 4 + 2) * WSTR + cb] = (short)p23;
        XLa[tile][(quad * 4 + 3) * WSTR + cb] = (short)(p23 >> 16);
    }
    __syncthreads();    // xx tile complete (both halves) + PS visible

    short8 a0 = *(const short8*)&XLa[tile][l15 * WSTR + quad * 8];
    short8 a1 = *(const short8*)&XLa[tile][l15 * WSTR + 32 + quad * 8];

    // pe_[i][r] = PE2 at (row = rb+quad*4+r, ch = (nt0+i)*16+l15)
    float p10[4], p11[4], p12[4];
    #pragma unroll
    for (int r = 0; r < 4; r++) {
        p10[r] = PS[tile][(quad * 4 + r) * 4 + 0];
        p11[r] = PS[tile][(quad * 4 + r) * 4 + 1];
        p12[r] = PS[tile][(quad * 4 + r) * 4 + 2];
    }
    float pe_[2][4];
    #pragma unroll
    for (int i = 0; i < 2; i++)
        #pragma unroll
        for (int r = 0; r < 4; r++)
            pe_[i][r] = fmaxf((p10[r] * w2c0[i] + p11[r] * w2c1[i] + p12[r] * w2c2[i])
                               * s2c[i] + sh2c[i], 0.f);

    // ---- Q (fully folded): Q1f = xx @ WQ1^T + bQ1 (this wave's 2 nt)
    #pragma unroll
    for (int i = 0; i < 2; i++) {
        int nt = nt0 + i;
        short8 b0 = *(const short8*)&wfrag[WQ_S + (size_t)((nt) * 64 + lane) * 8];
        short8 b1 = *(const short8*)&wfrag[WQ_S + (size_t)((4 + nt) * 64 + lane) * 8];
        f32x4 c = (f32x4){0.f, 0.f, 0.f, 0.f};
        c = MFMA(a0, b0, c); c = MFMA(a1, b1, c);
        unsigned int p01 = pk_bf16(c[0] + bq1c[i], c[1] + bq1c[i]);
        unsigned int p23 = pk_bf16(c[2] + bq1c[i], c[3] + bq1c[i]);
        q1f_out[(unsigned)(rb + quad * 4 + 0) * 64u + nt * 16 + l15] = (short)p01;
        q1f_out[(unsigned)(rb + quad * 4 + 1) * 64u + nt * 16 + l15] = (short)(p01 >> 16);
        q1f_out[(unsigned)(rb + quad * 4 + 2) * 64u + nt * 16 + l15] = (short)p23;
        q1f_out[(unsigned)(rb + quad * 4 + 3) * 64u + nt * 16 + l15] = (short)(p23 >> 16);
    }

    // ---- K': k' = xx@w_k^T + b_k + pe -> XLb (this wave's 2 nt)
    #pragma unroll
    for (int i = 0; i < 2; i++) {
        int nt = nt0 + i;
        short8 b0 = *(const short8*)&wfrag[WK_S + (size_t)((nt) * 64 + lane) * 8];
        short8 b1 = *(const short8*)&wfrag[WK_S + (size_t)((4 + nt) * 64 + lane) * 8];
        f32x4 c = (f32x4){0.f, 0.f, 0.f, 0.f};
        c = MFMA(a0, b0, c); c = MFMA(a1, b1, c);
        unsigned int p01 = pk_bf16(c[0] + bkc[i] + pe_[i][0], c[1] + bkc[i] + pe_[i][1]);
        unsigned int p23 = pk_bf16(c[2] + bkc[i] + pe_[i][2], c[3] + bkc[i] + pe_[i][3]);
        int cb = nt * 16 + l15;
        XLb[tile][(quad * 4 + 0) * WSTR + cb] = (short)p01;
        XLb[tile][(quad * 4 + 1) * WSTR + cb] = (short)(p01 >> 16);
        XLb[tile][(quad * 4 + 2) * WSTR + cb] = (short)p23;
        XLb[tile][(quad * 4 + 3) * WSTR + cb] = (short)(p23 >> 16);
    }
    __syncthreads();    // k' tile complete (both halves)

    short8 ak0 = *(const short8*)&XLb[tile][l15 * WSTR + quad * 8];
    short8 ak1 = *(const short8*)&XLb[tile][l15 * WSTR + 32 + quad * 8];

    // ---- K1 = k' @ W1s^T (this wave's 2 nt, keep in regs)
    float k1f[2][4];
    #pragma unroll
    for (int i = 0; i < 2; i++) {
        int nt = nt0 + i;
        short8 b0 = *(const short8*)&wfrag[GA1_S + (size_t)((nt) * 64 + lane) * 8];
        short8 b1 = *(const short8*)&wfrag[GA1_S + (size_t)((4 + nt) * 64 + lane) * 8];
        f32x4 c = (f32x4){0.f, 0.f, 0.f, 0.f};
        c = MFMA(ak0, b0, c); c = MFMA(ak1, b1, c);
        #pragma unroll
        for (int r = 0; r < 4; r++) k1f[i][r] = c[r];
    }

    // ---- V: vp = xx@w_v^T + b_v + pe; pack kv = (bf16(K1) | bf16(vp)<<16)
    #pragma unroll
    for (int i = 0; i < 2; i++) {
        int nt = nt0 + i;
        short8 b0 = *(const short8*)&wfrag[WV_S + (size_t)((nt) * 64 + lane) * 8];
        short8 b1 = *(const short8*)&wfrag[WV_S + (size_t)((4 + nt) * 64 + lane) * 8];
        f32x4 c = (f32x4){0.f, 0.f, 0.f, 0.f};
        c = MFMA(a0, b0, c); c = MFMA(a1, b1, c);
        #pragma unroll
        for (int r = 0; r < 4; r++) {
            float vv = c[r] + bvc[i] + pe_[i][r];
            kv_out[(unsigned)(rb + quad * 4 + r) * 64u + nt * 16 + l15] =
                pk_bf16(k1f[i][r], vv);
        }
    }
}

// ---------------------------------------------------------------------------
// Kernel 2: per-point attention + fused out-projection (R9-verified best,
// UNCHANGED). W2s B-frags staged in LDS; beta2 per-lane in regs; Wb
// ping-pong; native exp2. LDS ~28.9 KB. grid = 4096 x 256.
// ---------------------------------------------------------------------------
#define GATHER(KVN, IT2)                                                      \
    _Pragma("unroll")                                                         \
    for (int j = 0; j < KNB; j++) {                                           \
        int mj = __builtin_amdgcn_readlane(m_all, (IT2) * 16 + j);            \
        KVN[j] = kvbuf[(unsigned)mj * 64u + (unsigned)lane];                  \
    }

#define ATTN_POINT(IT, KV, QV, WB)                                            \
    {                                                                         \
        short* wb_ = (WB);                                                    \
        _Pragma("unroll")                                                     \
        for (int j = 0; j < KNB; j += 2) {                                    \
            float h0 = fmaxf(__builtin_bit_cast(float, KV[j] << 16) - (QV), 0.f);     \
            float h1 = fmaxf(__builtin_bit_cast(float, KV[j + 1] << 16) - (QV), 0.f); \
            unsigned pkw = pk_bf16(h0, h1);                                   \
            wb_[(j) * WSTR + lane] = (short)pkw;                              \
            wb_[(j + 1) * WSTR + lane] = (short)(pkw >> 16);                  \
        }                                                                     \
        short8 c0 = *(const short8*)&wb_[l15 * WSTR + quad * 8];              \
        short8 c1 = *(const short8*)&wb_[l15 * WSTR + 32 + quad * 8];         \
        float smv[4][4];                                                      \
        _Pragma("unroll")                                                     \
        for (int nt = 0; nt < 4; nt++) {                                      \
            short8 b0 = *(const short8*)&BW[(size_t)((nt) * 64 + lane) * 8];  \
            short8 b1 = *(const short8*)&BW[(size_t)((4 + nt) * 64 + lane) * 8]; \
            f32x4 c = (f32x4){0.f, 0.f, 0.f, 0.f};                            \
            c = MFMA(c0, b0, c); c = MFMA(c1, b1, c);                         \
            _Pragma("unroll")                                                 \
            for (int r = 0; r < 4; r++)                                       \
                smv[nt][r] = fmaxf(c[r] + b2c[nt], 0.f);                      \
        }                                                                     \
        float sarr[4];                                                        \
        _Pragma("unroll")                                                     \
        for (int nt = 0; nt < 4; nt++) {                                      \
            float e0 = exp2fast(smv[nt][0]), e1 = exp2fast(smv[nt][1]);       \
            float e2 = exp2fast(smv[nt][2]), e3 = exp2fast(smv[nt][3]);       \
            float s = e0 + e1 + e2 + e3;                                      \
            s += __shfl_xor(s, 16);                                           \
            s += __shfl_xor(s, 32);                                           \
            sarr[nt] = s;                                                     \
            unsigned p01 = pk_bf16(e0, e1);                                   \
            unsigned p23 = pk_bf16(e2, e3);                                   \
            wb_[(quad * 4 + 0) * WSTR + nt * 16 + l15] = (short)p01;          \
            wb_[(quad * 4 + 1) * WSTR + nt * 16 + l15] = (short)(p01 >> 16);  \
            wb_[(quad * 4 + 2) * WSTR + nt * 16 + l15] = (short)p23;          \
            wb_[(quad * 4 + 3) * WSTR + nt * 16 + l15] = (short)(p23 >> 16);  \
        }                                                                     \
        float oacc = 0.f;                                                     \
        _Pragma("unroll")                                                     \
        for (int j = 0; j < KNB; j++)                                         \
            oacc += __builtin_bit_cast(float, KV[j] & 0xffff0000u)            \
                    * bf2f((unsigned short)wb_[j * WSTR + lane]);             \
        float s01 = (quad == 0) ? sarr[0] : sarr[1];                          \
        float s23 = (quad == 2) ? sarr[2] : sarr[3];                          \
        float ssel = (quad < 2) ? s01 : s23;                                  \
        OM[((IT) * 4 + wave) * WSTR + lane] = f2bf(oacc * (1.0f / ssel));     \
    }

__global__ __launch_bounds__(256) void k_attn(
    const int* __restrict__ idx,
    const unsigned short* __restrict__ q1f,
    const unsigned* __restrict__ kvbuf, const short* __restrict__ wfrag,
    const float* __restrict__ ga_b2, const float* __restrict__ ga_g2,
    const float* __restrict__ ga_be2, const float* __restrict__ ga_m2,
    const float* __restrict__ ga_v2,
    const float* __restrict__ feats, float* __restrict__ out)
{
    __shared__ __align__(16) short BW[512 * 8];          // 8 KB: W2s frags (LDS)
    __shared__ __align__(16) short Wb[4][2][16 * WSTR];  // 18.4 KB ping-pong
    __shared__ __align__(16) short OM[16 * WSTR];        // 2.3 KB om row tile
    const int tid = threadIdx.x;
    const int wave = tid >> 6, lane = tid & 63;
    const int l15 = lane & 15, quad = lane >> 4;

    #pragma unroll
    for (int rep = 0; rep < 2; rep++) {
        int e = rep * 256 + tid;
        *(short8*)&BW[(size_t)e * 8] = *(const short8*)&wfrag[GA2_S + (size_t)e * 8];
    }

    // beta2 (folded, log2e-scaled) per-lane: channels nt*16+l15
    float b2c[4];
    #pragma unroll
    for (int nt = 0; nt < 4; nt++) {
        int ch = nt * 16 + l15;
        float s2 = ga_g2[ch] * rsqrtf(ga_v2[ch] + 1e-5f);
        b2c[nt] = (ga_b2[ch] * s2 + ga_be2[ch] - ga_m2[ch] * s2) * LOG2E;
    }

    const int n0 = blockIdx.x * 16 + wave;
    // all 4 iterations' neighbor indices in one wave-wide load:
    // lane (it2*16+j) holds idx[n0 + it2*4][j]
    int m_all = idx[(unsigned)(n0 + (lane >> 4) * 4) * 16u + (unsigned)(lane & 15)];
    float qf0 = bf2f(q1f[(unsigned)(n0     ) * 64u + lane]);
    float qf1 = bf2f(q1f[(unsigned)(n0 +  4) * 64u + lane]);
    float qf2 = bf2f(q1f[(unsigned)(n0 +  8) * 64u + lane]);
    float qf3 = bf2f(q1f[(unsigned)(n0 + 12) * 64u + lane]);
    __syncthreads();

    unsigned kvA[KNB], kvB[KNB];
    GATHER(kvA, 0)
    GATHER(kvB, 1)
    ATTN_POINT(0, kvA, qf0, &Wb[wave][0][0])
    GATHER(kvA, 2)
    ATTN_POINT(1, kvB, qf1, &Wb[wave][1][0])
    GATHER(kvB, 3)
    ATTN_POINT(2, kvA, qf2, &Wb[wave][0][0])
    ATTN_POINT(3, kvB, qf3, &Wb[wave][1][0])

    // ---- fused out-projection: out[16 x 256] = OM @ w_out^T + feats ----
    __syncthreads();
    short8 A0 = *(const short8*)&OM[l15 * WSTR + quad * 8];
    short8 A1 = *(const short8*)&OM[l15 * WSTR + 32 + quad * 8];
    const int rb = blockIdx.x * 16;
    #pragma unroll
    for (int t = 0; t < 4; t++) {
        int nt = wave * 4 + t;   // column tile 0..15 split across the 4 waves
        short8 b0 = *(const short8*)&wfrag[WOUT_S + (size_t)((nt * 2 + 0) * 64 + lane) * 8];
        short8 b1 = *(const short8*)&wfrag[WOUT_S + (size_t)((nt * 2 + 1) * 64 + lane) * 8];
        f32x4 c = (f32x4){0.f, 0.f, 0.f, 0.f};
        c = MFMA(A0, b0, c);
        c = MFMA(A1, b1, c);
        #pragma unroll
        for (int r = 0; r < 4; r++) {
            size_t off = (size_t)(rb + quad * 4 + r) * INC + nt * 16 + l15;
            out[off] = c[r] + feats[off];
        }
    }
}

extern "C" void kernel_launch(void* const* d_in, const int* in_sizes, int n_in,
                              void* d_out, int out_size, void* d_ws, size_t ws_size,
                              hipStream_t stream)
{
    const float* feats = (const float*)d_in[0];
    const float* pos   = (const float*)d_in[1];
    const int*   idx   = (const int*)d_in[2];
    const float* w_in  = (const float*)d_in[3];
    const float* w_q   = (const float*)d_in[4];
    const float* b_q   = (const float*)d_in[5];
    const float* w_k   = (const float*)d_in[6];
    const float* b_k   = (const float*)d_in[7];
    const float* w_v   = (const float*)d_in[8];
    const float* b_v   = (const float*)d_in[9];
    const float* pe_w1 = (const float*)d_in[10];
    const float* pe_b1 = (const float*)d_in[11];
    const float* pe_g1 = (const float*)d_in[12];
    const float* pe_be1= (const float*)d_in[13];
    const float* pe_m1 = (const float*)d_in[14];
    const float* pe_v1 = (const float*)d_in[15];
    const float* pe_w2 = (const float*)d_in[16];
    const float* pe_b2 = (const float*)d_in[17];
    const float* pe_g2 = (const float*)d_in[18];
    const float* pe_be2= (const float*)d_in[19];
    const float* pe_m2 = (const float*)d_in[20];
    const float* pe_v2 = (const float*)d_in[21];
    const float* ga_w1 = (const float*)d_in[22];
    const float* ga_b1 = (const float*)d_in[23];
    const float* ga_g1 = (const float*)d_in[24];
    const float* ga_be1= (const float*)d_in[25];
    const float* ga_m1 = (const float*)d_in[26];
    const float* ga_v1 = (const float*)d_in[27];
    const float* ga_w2 = (const float*)d_in[28];
    const float* ga_b2 = (const float*)d_in[29];
    const float* ga_g2 = (const float*)d_in[30];
    const float* ga_be2= (const float*)d_in[31];
    const float* ga_m2 = (const float*)d_in[32];
    const float* ga_v2 = (const float*)d_in[33];
    const float* w_out = (const float*)d_in[34];

    char* ws = (char*)d_ws;
    short*    q1f  = (short*)(ws);                            // 8 MB
    unsigned* kv   = (unsigned*)(ws + (size_t) 8 * 1024 * 1024); // 16 MB
    short*    wbuf = (short*)(ws + (size_t)24 * 1024 * 1024); // ~107 KB frag buffer

    k_prep<<<27, 256, 0, stream>>>(w_in, w_q, w_k, w_v, ga_w1, ga_w2, w_out, b_q,
                                   ga_g1, ga_v1, ga_b1, ga_be1, ga_m1,
                                   ga_g2, ga_v2, wbuf);
    k_qkv<<<NPTS / 32, 256, 0, stream>>>(feats, wbuf, pos, b_k, b_v,
                                         pe_w1, pe_b1, pe_g1, pe_be1, pe_m1, pe_v1,
                                         pe_w2, pe_b2, pe_g2, pe_be2, pe_m2, pe_v2,
                                         q1f, kv);
    k_attn<<<NPTS / 16, 256, 0, stream>>>(idx,
                                          (const unsigned short*)q1f, kv, wbuf,
                                          ga_b2, ga_g2, ga_be2, ga_m2, ga_v2,
                                          feats, (float*)d_out);
}

// Round 14
// 246.007 us; speedup vs baseline: 1.0345x; 1.0345x over previous
//
#include <hip/hip_runtime.h>

#define NPTS 65536
#define INC  256
#define MID  64
#define KNB  16
#define WSTR 72   // padded LDS row stride (shorts)

// fragment-buffer offsets in shorts (workspace, written by k_prep)
#define WIN_S   0        // w_in   2048 entries
#define WQ_S    16384    // WQ1 = W1s @ w_q (fully folded Q)   512
#define WK_S    20480    // w_k     512
#define WV_S    24576    // w_v     512
#define GA1_S   28672    // ga_w1 * s1 (bn1-folded)   512
#define GA2_S   32768    // ga_w2 * s2 * log2(e)      512
#define WOUT_S  36864    // w_out  2048
#define NFRAG_ENT 6656
#define BQ1F_S  53248    // combined Q bias, 64 floats (short offset, 4B-aligned)

#define LOG2E 1.44269504088896340736f

typedef __attribute__((ext_vector_type(8))) short short8;
typedef __attribute__((ext_vector_type(4))) float f32x4;

#define MFMA(a, b, c) __builtin_amdgcn_mfma_f32_16x16x32_bf16((a), (b), (c), 0, 0, 0)
#define WBAR() __builtin_amdgcn_wave_barrier()

__device__ inline float bf2f(unsigned short s) {
    unsigned int u = ((unsigned int)s) << 16;
    return __builtin_bit_cast(float, u);
}
// HW packed f32->bf16 (RNE), 1 VALU op for 2 values
__device__ inline unsigned int pk_bf16(float lo, float hi) {
    unsigned int r;
    asm("v_cvt_pk_bf16_f32 %0, %1, %2" : "=v"(r) : "v"(lo), "v"(hi));
    return r;
}
__device__ inline short f2bf(float f) { return (short)pk_bf16(f, f); }
// native 2^x (v_exp_f32 IS exp2 on gfx950)
__device__ inline float exp2fast(float x) {
    float r;
    asm("v_exp_f32 %0, %1" : "=v"(r) : "v"(x));
    return r;
}

__device__ inline short8 cvtf8(f32x4 a, f32x4 b) {
    union { unsigned int u[4]; short8 s; } r;
    r.u[0] = pk_bf16(a[0], a[1]); r.u[1] = pk_bf16(a[2], a[3]);
    r.u[2] = pk_bf16(b[0], b[1]); r.u[3] = pk_bf16(b[2], b[3]);
    return r.s;
}
__device__ inline short8 load_cvt8(const float* __restrict__ p) {
    const f32x4* v = (const f32x4*)p;
    return cvtf8(v[0], v[1]);
}
__device__ inline short8 load_cvt8s(const float* __restrict__ p, float scale) {
    const f32x4* v = (const f32x4*)p;
    f32x4 a = v[0], b = v[1];
    #pragma unroll
    for (int i = 0; i < 4; i++) { a[i] *= scale; b[i] *= scale; }
    return cvtf8(a, b);
}

// ---------------------------------------------------------------------------
// Kernel 0: weights -> bf16 MFMA B-fragment order.
//   seg0: WQ1 = (s1*ga_w1) @ w_q   (Q projection fully folded through bn1)
//   seg3: ga_w1 * s1;  seg4: ga_w2 * s2 * log2(e)  (exp -> native exp2)
//   tail: bQ1[ch] = (s1*ga_w1[ch,:])·b_q - beta1[ch]   (64 floats)
// ---------------------------------------------------------------------------
__global__ __launch_bounds__(256) void k_prep(
    const float* __restrict__ w_in, const float* __restrict__ w_q,
    const float* __restrict__ w_k, const float* __restrict__ w_v,
    const float* __restrict__ ga_w1, const float* __restrict__ ga_w2,
    const float* __restrict__ w_out, const float* __restrict__ b_q,
    const float* __restrict__ ga_g1, const float* __restrict__ ga_v1,
    const float* __restrict__ ga_b1, const float* __restrict__ ga_be1,
    const float* __restrict__ ga_m1,
    const float* __restrict__ ga_g2, const float* __restrict__ ga_v2,
    short* __restrict__ wbuf)
{
    int gid = blockIdx.x * 256 + threadIdx.x;
    if (gid >= NFRAG_ENT + 64) return;
    if (gid < 2048) {                               // w_in [64][256]
        int e = gid, f = e >> 6, ln = e & 63;
        int nt = f & 3, ks = f >> 2;
        int row = nt * 16 + (ln & 15), col = ks * 32 + (ln >> 4) * 8;
        *(short8*)&wbuf[(size_t)gid * 8] = load_cvt8(w_in + (size_t)row * INC + col);
    } else if (gid < 4608) {                        // five [64][64] matrices
        int seg = (gid - 2048) >> 9;
        int e = (gid - 2048) & 511;
        int f = e >> 6, ln = e & 63;
        int nt = f & 3, ks = f >> 2;
        int row = nt * 16 + (ln & 15), col = ks * 32 + (ln >> 4) * 8;
        if (seg == 0) {
            // WQ1[row][col+o] = s1[row] * sum_c ga_w1[row][c] * w_q[c][col+o]
            float s1r = ga_g1[row] * rsqrtf(ga_v1[row] + 1e-5f);
            float accv[8];
            #pragma unroll
            for (int o = 0; o < 8; o++) accv[o] = 0.f;
            for (int c = 0; c < 64; c++) {
                float a = ga_w1[(size_t)row * MID + c] * s1r;
                #pragma unroll
                for (int o = 0; o < 8; o++)
                    accv[o] += a * w_q[(size_t)c * MID + col + o];
            }
            f32x4 lo = {accv[0], accv[1], accv[2], accv[3]};
            f32x4 hi = {accv[4], accv[5], accv[6], accv[7]};
            *(short8*)&wbuf[(size_t)gid * 8] = cvtf8(lo, hi);
        } else {
            const float* m = seg == 1 ? w_k : seg == 2 ? w_v
                           : seg == 3 ? ga_w1 : ga_w2;
            float scale = 1.f;
            if (seg == 3)      scale = ga_g1[row] * rsqrtf(ga_v1[row] + 1e-5f);
            else if (seg == 4) scale = ga_g2[row] * rsqrtf(ga_v2[row] + 1e-5f) * LOG2E;
            *(short8*)&wbuf[(size_t)gid * 8] = load_cvt8s(m + (size_t)row * MID + col, scale);
        }
    } else if (gid < NFRAG_ENT) {                   // w_out [256][64]
        int e = gid - 4608, f = e >> 6, ln = e & 63;
        int nt = f >> 1, ks = f & 1;
        int row = nt * 16 + (ln & 15), col = ks * 32 + (ln >> 4) * 8;
        *(short8*)&wbuf[(size_t)gid * 8] = load_cvt8(w_out + (size_t)row * MID + col);
    } else {                                        // combined Q bias (64 floats)
        int ch = gid - NFRAG_ENT;
        float s1r = ga_g1[ch] * rsqrtf(ga_v1[ch] + 1e-5f);
        float acc = 0.f;
        for (int c = 0; c < 64; c++) acc += ga_w1[(size_t)ch * MID + c] * b_q[c];
        float beta1 = (ga_b1[ch] - ga_m1[ch]) * s1r + ga_be1[ch];
        ((float*)(wbuf + BQ1F_S))[ch] = s1r * acc - beta1;
    }
}

// ---------------------------------------------------------------------------
// Kernel 1: per 16-row tile compute
//   xx  = feats @ w_in^T
//   Q1f = xx @ WQ1^T + bQ1                    [bf16 out]  (single MFMA stage)
//   K1  = (xx @ w_k^T + b_k + pe) @ W1s^T     -> lo half of kv
//   vp  =  xx @ w_v^T + b_v + pe              -> hi half of kv
// block = 256 (4 waves), 1 row-tile/wave; grid = 1024.
// ---------------------------------------------------------------------------
__global__ __launch_bounds__(256) void k_qkv(
    const float* __restrict__ feats, const short* __restrict__ wfrag,
    const float* __restrict__ pos,
    const float* __restrict__ b_k, const float* __restrict__ b_v,
    const float* __restrict__ pe_w1, const float* __restrict__ pe_b1,
    const float* __restrict__ pe_g1, const float* __restrict__ pe_be1,
    const float* __restrict__ pe_m1, const float* __restrict__ pe_v1,
    const float* __restrict__ pe_w2, const float* __restrict__ pe_b2,
    const float* __restrict__ pe_g2, const float* __restrict__ pe_be2,
    const float* __restrict__ pe_m2, const float* __restrict__ pe_v2,
    short* __restrict__ q1f_out, unsigned* __restrict__ kv_out)
{
    __shared__ __align__(16) short XL[4][16 * WSTR];  // wave-private staging
    __shared__ float PS[4][16 * 4];                   // PE1 per row
    const int tid = threadIdx.x;
    const int wave = tid >> 6, lane = tid & 63;
    const int l15 = lane & 15, quad = lane >> 4;
    const int rb = (blockIdx.x * 4 + wave) * 16;

    // PE1 for the 16 rows of this wave (wave-private LDS, lockstep-safe)
    if (lane < 16) {
        float s0 = pe_g1[0] * rsqrtf(pe_v1[0] + 1e-5f);
        float s1 = pe_g1[1] * rsqrtf(pe_v1[1] + 1e-5f);
        float sc = pe_g1[2] * rsqrtf(pe_v1[2] + 1e-5f);
        float px = pos[(size_t)(rb + lane) * 3 + 0];
        float py = pos[(size_t)(rb + lane) * 3 + 1];
        float pz = pos[(size_t)(rb + lane) * 3 + 2];
        PS[wave][lane * 4 + 0] =
            fmaxf((px * pe_w1[0] + py * pe_w1[1] + pz * pe_w1[2] + pe_b1[0] - pe_m1[0]) * s0 + pe_be1[0], 0.f);
        PS[wave][lane * 4 + 1] =
            fmaxf((px * pe_w1[3] + py * pe_w1[4] + pz * pe_w1[5] + pe_b1[1] - pe_m1[1]) * s1 + pe_be1[1], 0.f);
        PS[wave][lane * 4 + 2] =
            fmaxf((px * pe_w1[6] + py * pe_w1[7] + pz * pe_w1[8] + pe_b1[2] - pe_m1[2]) * sc + pe_be1[2], 0.f);
    }

    // per-lane channel params (ch = nt*16 + l15)
    const float* bq1f = (const float*)(wfrag + BQ1F_S);
    float w2c0[4], w2c1[4], w2c2[4], s2c[4], sh2c[4], bq1c[4], bkc[4], bvc[4];
    #pragma unroll
    for (int nt = 0; nt < 4; nt++) {
        int ch = nt * 16 + l15;
        w2c0[nt] = pe_w2[ch * 3 + 0]; w2c1[nt] = pe_w2[ch * 3 + 1]; w2c2[nt] = pe_w2[ch * 3 + 2];
        float s2 = pe_g2[ch] * rsqrtf(pe_v2[ch] + 1e-5f);
        s2c[nt] = s2;
        sh2c[nt] = (pe_b2[ch] - pe_m2[ch]) * s2 + pe_be2[ch];
        bq1c[nt] = bq1f[ch];
        bkc[nt] = b_k[ch]; bvc[nt] = b_v[ch];
    }

    // xx = feats @ w_in^T
    f32x4 acc[4];
    #pragma unroll
    for (int nt = 0; nt < 4; nt++) acc[nt] = (f32x4){0.f, 0.f, 0.f, 0.f};
    const float* arow = feats + (size_t)(rb + l15) * INC + quad * 8;
    #pragma unroll
    for (int ks = 0; ks < 8; ks++) {
        short8 a = load_cvt8(arow + ks * 32);
        #pragma unroll
        for (int nt = 0; nt < 4; nt++) {
            short8 b = *(const short8*)&wfrag[WIN_S + (size_t)((ks * 4 + nt) * 64 + lane) * 8];
            acc[nt] = MFMA(a, b, acc[nt]);
        }
    }
    #pragma unroll
    for (int nt = 0; nt < 4; nt++) {
        unsigned int p01 = pk_bf16(acc[nt][0], acc[nt][1]);
        unsigned int p23 = pk_bf16(acc[nt][2], acc[nt][3]);
        XL[wave][(quad * 4 + 0) * WSTR + nt * 16 + l15] = (short)p01;
        XL[wave][(quad * 4 + 1) * WSTR + nt * 16 + l15] = (short)(p01 >> 16);
        XL[wave][(quad * 4 + 2) * WSTR + nt * 16 + l15] = (short)p23;
        XL[wave][(quad * 4 + 3) * WSTR + nt * 16 + l15] = (short)(p23 >> 16);
    }
    WBAR();
    short8 a0 = *(const short8*)&XL[wave][l15 * WSTR + quad * 8];
    short8 a1 = *(const short8*)&XL[wave][l15 * WSTR + 32 + quad * 8];
    WBAR();

    // pe[nt][r] = PE2 at (row = rb+quad*4+r, ch = nt*16+l15)
    float p10[4], p11[4], p12[4];
    #pragma unroll
    for (int r = 0; r < 4; r++) {
        p10[r] = PS[wave][(quad * 4 + r) * 4 + 0];
        p11[r] = PS[wave][(quad * 4 + r) * 4 + 1];
        p12[r] = PS[wave][(quad * 4 + r) * 4 + 2];
    }
    float pe_[4][4];
    #pragma unroll
    for (int nt = 0; nt < 4; nt++)
        #pragma unroll
        for (int r = 0; r < 4; r++)
            pe_[nt][r] = fmaxf((p10[r] * w2c0[nt] + p11[r] * w2c1[nt] + p12[r] * w2c2[nt])
                               * s2c[nt] + sh2c[nt], 0.f);

    // ---- Q (fully folded): Q1f = xx @ WQ1^T + bQ1  -- single MFMA stage
    #pragma unroll
    for (int nt = 0; nt < 4; nt++) {
        short8 b0 = *(const short8*)&wfrag[WQ_S + (size_t)((nt) * 64 + lane) * 8];
        short8 b1 = *(const short8*)&wfrag[WQ_S + (size_t)((4 + nt) * 64 + lane) * 8];
        f32x4 c = (f32x4){0.f, 0.f, 0.f, 0.f};
        c = MFMA(a0, b0, c); c = MFMA(a1, b1, c);
        unsigned int p01 = pk_bf16(c[0] + bq1c[nt], c[1] + bq1c[nt]);
        unsigned int p23 = pk_bf16(c[2] + bq1c[nt], c[3] + bq1c[nt]);
        q1f_out[(unsigned)(rb + quad * 4 + 0) * 64u + nt * 16 + l15] = (short)p01;
        q1f_out[(unsigned)(rb + quad * 4 + 1) * 64u + nt * 16 + l15] = (short)(p01 >> 16);
        q1f_out[(unsigned)(rb + quad * 4 + 2) * 64u + nt * 16 + l15] = (short)p23;
        q1f_out[(unsigned)(rb + quad * 4 + 3) * 64u + nt * 16 + l15] = (short)(p23 >> 16);
    }

    // ---- K chain: k' = xx@w_k^T + b_k + pe  ->  K1 = k'@W1s^T (keep in regs)
    WBAR();
    #pragma unroll
    for (int nt = 0; nt < 4; nt++) {
        short8 b0 = *(const short8*)&wfrag[WK_S + (size_t)((nt) * 64 + lane) * 8];
        short8 b1 = *(const short8*)&wfrag[WK_S + (size_t)((4 + nt) * 64 + lane) * 8];
        f32x4 c = (f32x4){0.f, 0.f, 0.f, 0.f};
        c = MFMA(a0, b0, c); c = MFMA(a1, b1, c);
        unsigned int p01 = pk_bf16(c[0] + bkc[nt] + pe_[nt][0], c[1] + bkc[nt] + pe_[nt][1]);
        unsigned int p23 = pk_bf16(c[2] + bkc[nt] + pe_[nt][2], c[3] + bkc[nt] + pe_[nt][3]);
        XL[wave][(quad * 4 + 0) * WSTR + nt * 16 + l15] = (short)p01;
        XL[wave][(quad * 4 + 1) * WSTR + nt * 16 + l15] = (short)(p01 >> 16);
        XL[wave][(quad * 4 + 2) * WSTR + nt * 16 + l15] = (short)p23;
        XL[wave][(quad * 4 + 3) * WSTR + nt * 16 + l15] = (short)(p23 >> 16);
    }
    WBAR();
    short8 ak0 = *(const short8*)&XL[wave][l15 * WSTR + quad * 8];
    short8 ak1 = *(const short8*)&XL[wave][l15 * WSTR + 32 + quad * 8];
    WBAR();
    float k1f[4][4];
    #pragma unroll
    for (int nt = 0; nt < 4; nt++) {
        short8 b0 = *(const short8*)&wfrag[GA1_S + (size_t)((nt) * 64 + lane) * 8];
        short8 b1 = *(const short8*)&wfrag[GA1_S + (size_t)((4 + nt) * 64 + lane) * 8];
        f32x4 c = (f32x4){0.f, 0.f, 0.f, 0.f};
        c = MFMA(ak0, b0, c); c = MFMA(ak1, b1, c);
        #pragma unroll
        for (int r = 0; r < 4; r++) k1f[nt][r] = c[r];
    }

    // ---- V: vp = xx@w_v^T + b_v + pe; pack kv = (bf16(K1) | bf16(vp)<<16)
    #pragma unroll
    for (int nt = 0; nt < 4; nt++) {
        short8 b0 = *(const short8*)&wfrag[WV_S + (size_t)((nt) * 64 + lane) * 8];
        short8 b1 = *(const short8*)&wfrag[WV_S + (size_t)((4 + nt) * 64 + lane) * 8];
        f32x4 c = (f32x4){0.f, 0.f, 0.f, 0.f};
        c = MFMA(a0, b0, c); c = MFMA(a1, b1, c);
        #pragma unroll
        for (int r = 0; r < 4; r++) {
            float vv = c[r] + bvc[nt] + pe_[nt][r];
            kv_out[(unsigned)(rb + quad * 4 + r) * 64u + nt * 16 + l15] =
                pk_bf16(k1f[nt][r], vv);
        }
    }
}

// ---------------------------------------------------------------------------
// Kernel 2: per-point attention + fused out-projection (R9-verified best).
//   l1out = relu(K1[m] - Q1f[n]);  logit2 = relu(l1out @ (W2s*log2e)^T + b2');
//   e = 2^logit2 (native v_exp_f32); softmax denominators via shfl;
//   om = sum_j vp[m_j]*e_j / s  -> LDS OM tile;  out = OM @ w_out^T + feats.
// W2s B-frags staged in LDS (BW); beta2 per-lane in regs; Wb ping-pong.
// LDS ~28.9 KB. block = 256 (4 waves), 1 pt/wave x 4 iters; grid = 4096.
// ---------------------------------------------------------------------------
#define GATHER(KVN, IT2)                                                      \
    _Pragma("unroll")                                                         \
    for (int j = 0; j < KNB; j++) {                                           \
        int mj = __builtin_amdgcn_readlane(m_all, (IT2) * 16 + j);            \
        KVN[j] = kvbuf[(unsigned)mj * 64u + (unsigned)lane];                  \
    }

#define ATTN_POINT(IT, KV, QV, WB)                                            \
    {                                                                         \
        short* wb_ = (WB);                                                    \
        _Pragma("unroll")                                                     \
        for (int j = 0; j < KNB; j += 2) {                                    \
            float h0 = fmaxf(__builtin_bit_cast(float, KV[j] << 16) - (QV), 0.f);     \
            float h1 = fmaxf(__builtin_bit_cast(float, KV[j + 1] << 16) - (QV), 0.f); \
            unsigned pkw = pk_bf16(h0, h1);                                   \
            wb_[(j) * WSTR + lane] = (short)pkw;                              \
            wb_[(j + 1) * WSTR + lane] = (short)(pkw >> 16);                  \
        }                                                                     \
        short8 c0 = *(const short8*)&wb_[l15 * WSTR + quad * 8];              \
        short8 c1 = *(const short8*)&wb_[l15 * WSTR + 32 + quad * 8];         \
        float smv[4][4];                                                      \
        _Pragma("unroll")                                                     \
        for (int nt = 0; nt < 4; nt++) {                                      \
            short8 b0 = *(const short8*)&BW[(size_t)((nt) * 64 + lane) * 8];  \
            short8 b1 = *(const short8*)&BW[(size_t)((4 + nt) * 64 + lane) * 8]; \
            f32x4 c = (f32x4){0.f, 0.f, 0.f, 0.f};                            \
            c = MFMA(c0, b0, c); c = MFMA(c1, b1, c);                         \
            _Pragma("unroll")                                                 \
            for (int r = 0; r < 4; r++)                                       \
                smv[nt][r] = fmaxf(c[r] + b2c[nt], 0.f);                      \
        }                                                                     \
        float sarr[4];                                                        \
        _Pragma("unroll")                                                     \
        for (int nt = 0; nt < 4; nt++) {                                      \
            float e0 = exp2fast(smv[nt][0]), e1 = exp2fast(smv[nt][1]);       \
            float e2 = exp2fast(smv[nt][2]), e3 = exp2fast(smv[nt][3]);       \
            float s = e0 + e1 + e2 + e3;                                      \
            s += __shfl_xor(s, 16);                                           \
            s += __shfl_xor(s, 32);                                           \
            sarr[nt] = s;                                                     \
            unsigned p01 = pk_bf16(e0, e1);                                   \
            unsigned p23 = pk_bf16(e2, e3);                                   \
            wb_[(quad * 4 + 0) * WSTR + nt * 16 + l15] = (short)p01;          \
            wb_[(quad * 4 + 1) * WSTR + nt * 16 + l15] = (short)(p01 >> 16);  \
            wb_[(quad * 4 + 2) * WSTR + nt * 16 + l15] = (short)p23;          \
            wb_[(quad * 4 + 3) * WSTR + nt * 16 + l15] = (short)(p23 >> 16);  \
        }                                                                     \
        float oacc = 0.f;                                                     \
        _Pragma("unroll")                                                     \
        for (int j = 0; j < KNB; j++)                                         \
            oacc += __builtin_bit_cast(float, KV[j] & 0xffff0000u)            \
                    * bf2f((unsigned short)wb_[j * WSTR + lane]);             \
        float s01 = (quad == 0) ? sarr[0] : sarr[1];                          \
        float s23 = (quad == 2) ? sarr[2] : sarr[3];                          \
        float ssel = (quad < 2) ? s01 : s23;                                  \
        OM[((IT) * 4 + wave) * WSTR + lane] = f2bf(oacc * (1.0f / ssel));     \
    }

__global__ __launch_bounds__(256) void k_attn(
    const int* __restrict__ idx,
    const unsigned short* __restrict__ q1f,
    const unsigned* __restrict__ kvbuf, const short* __restrict__ wfrag,
    const float* __restrict__ ga_b2, const float* __restrict__ ga_g2,
    const float* __restrict__ ga_be2, const float* __restrict__ ga_m2,
    const float* __restrict__ ga_v2,
    const float* __restrict__ feats, float* __restrict__ out)
{
    __shared__ __align__(16) short BW[512 * 8];          // 8 KB: W2s frags (LDS)
    __shared__ __align__(16) short Wb[4][2][16 * WSTR];  // 18.4 KB ping-pong
    __shared__ __align__(16) short OM[16 * WSTR];        // 2.3 KB om row tile
    const int tid = threadIdx.x;
    const int wave = tid >> 6, lane = tid & 63;
    const int l15 = lane & 15, quad = lane >> 4;

    #pragma unroll
    for (int rep = 0; rep < 2; rep++) {
        int e = rep * 256 + tid;
        *(short8*)&BW[(size_t)e * 8] = *(const short8*)&wfrag[GA2_S + (size_t)e * 8];
    }

    // beta2 (folded, log2e-scaled) per-lane: channels nt*16+l15
    float b2c[4];
    #pragma unroll
    for (int nt = 0; nt < 4; nt++) {
        int ch = nt * 16 + l15;
        float s2 = ga_g2[ch] * rsqrtf(ga_v2[ch] + 1e-5f);
        b2c[nt] = (ga_b2[ch] * s2 + ga_be2[ch] - ga_m2[ch] * s2) * LOG2E;
    }

    const int n0 = blockIdx.x * 16 + wave;
    // all 4 iterations' neighbor indices in one wave-wide load:
    // lane (it2*16+j) holds idx[n0 + it2*4][j]
    int m_all = idx[(unsigned)(n0 + (lane >> 4) * 4) * 16u + (unsigned)(lane & 15)];
    float qf0 = bf2f(q1f[(unsigned)(n0     ) * 64u + lane]);
    float qf1 = bf2f(q1f[(unsigned)(n0 +  4) * 64u + lane]);
    float qf2 = bf2f(q1f[(unsigned)(n0 +  8) * 64u + lane]);
    float qf3 = bf2f(q1f[(unsigned)(n0 + 12) * 64u + lane]);
    __syncthreads();

    unsigned kvA[KNB], kvB[KNB];
    GATHER(kvA, 0)
    GATHER(kvB, 1)
    ATTN_POINT(0, kvA, qf0, &Wb[wave][0][0])
    GATHER(kvA, 2)
    ATTN_POINT(1, kvB, qf1, &Wb[wave][1][0])
    GATHER(kvB, 3)
    ATTN_POINT(2, kvA, qf2, &Wb[wave][0][0])
    ATTN_POINT(3, kvB, qf3, &Wb[wave][1][0])

    // ---- fused out-projection: out[16 x 256] = OM @ w_out^T + feats ----
    __syncthreads();
    short8 A0 = *(const short8*)&OM[l15 * WSTR + quad * 8];
    short8 A1 = *(const short8*)&OM[l15 * WSTR + 32 + quad * 8];
    const int rb = blockIdx.x * 16;
    #pragma unroll
    for (int t = 0; t < 4; t++) {
        int nt = wave * 4 + t;   // column tile 0..15 split across the 4 waves
        short8 b0 = *(const short8*)&wfrag[WOUT_S + (size_t)((nt * 2 + 0) * 64 + lane) * 8];
        short8 b1 = *(const short8*)&wfrag[WOUT_S + (size_t)((nt * 2 + 1) * 64 + lane) * 8];
        f32x4 c = (f32x4){0.f, 0.f, 0.f, 0.f};
        c = MFMA(A0, b0, c);
        c = MFMA(A1, b1, c);
        #pragma unroll
        for (int r = 0; r < 4; r++) {
            size_t off = (size_t)(rb + quad * 4 + r) * INC + nt * 16 + l15;
            out[off] = c[r] + feats[off];
        }
    }
}

extern "C" void kernel_launch(void* const* d_in, const int* in_sizes, int n_in,
                              void* d_out, int out_size, void* d_ws, size_t ws_size,
                              hipStream_t stream)
{
    const float* feats = (const float*)d_in[0];
    const float* pos   = (const float*)d_in[1];
    const int*   idx   = (const int*)d_in[2];
    const float* w_in  = (const float*)d_in[3];
    const float* w_q   = (const float*)d_in[4];
    const float* b_q   = (const float*)d_in[5];
    const float* w_k   = (const float*)d_in[6];
    const float* b_k   = (const float*)d_in[7];
    const float* w_v   = (const float*)d_in[8];
    const float* b_v   = (const float*)d_in[9];
    const float* pe_w1 = (const float*)d_in[10];
    const float* pe_b1 = (const float*)d_in[11];
    const float* pe_g1 = (const float*)d_in[12];
    const float* pe_be1= (const float*)d_in[13];
    const float* pe_m1 = (const float*)d_in[14];
    const float* pe_v1 = (const float*)d_in[15];
    const float* pe_w2 = (const float*)d_in[16];
    const float* pe_b2 = (const float*)d_in[17];
    const float* pe_g2 = (const float*)d_in[18];
    const float* pe_be2= (const float*)d_in[19];
    const float* pe_m2 = (const float*)d_in[20];
    const float* pe_v2 = (const float*)d_in[21];
    const float* ga_w1 = (const float*)d_in[22];
    const float* ga_b1 = (const float*)d_in[23];
    const float* ga_g1 = (const float*)d_in[24];
    const float* ga_be1= (const float*)d_in[25];
    const float* ga_m1 = (const float*)d_in[26];
    const float* ga_v1 = (const float*)d_in[27];
    const float* ga_w2 = (const float*)d_in[28];
    const float* ga_b2 = (const float*)d_in[29];
    const float* ga_g2 = (const float*)d_in[30];
    const float* ga_be2= (const float*)d_in[31];
    const float* ga_m2 = (const float*)d_in[32];
    const float* ga_v2 = (const float*)d_in[33];
    const float* w_out = (const float*)d_in[34];

    char* ws = (char*)d_ws;
    short*    q1f  = (short*)(ws);                            // 8 MB
    unsigned* kv   = (unsigned*)(ws + (size_t) 8 * 1024 * 1024); // 16 MB
    short*    wbuf = (short*)(ws + (size_t)24 * 1024 * 1024); // ~107 KB frag buffer

    k_prep<<<27, 256, 0, stream>>>(w_in, w_q, w_k, w_v, ga_w1, ga_w2, w_out, b_q,
                                   ga_g1, ga_v1, ga_b1, ga_be1, ga_m1,
                                   ga_g2, ga_v2, wbuf);
    k_qkv<<<NPTS / 64, 256, 0, stream>>>(feats, wbuf, pos, b_k, b_v,
                                         pe_w1, pe_b1, pe_g1, pe_be1, pe_m1, pe_v1,
                                         pe_w2, pe_b2, pe_g2, pe_be2, pe_m2, pe_v2,
                                         q1f, kv);
    k_attn<<<NPTS / 16, 256, 0, stream>>>(idx,
                                          (const unsigned short*)q1f, kv, wbuf,
                                          ga_b2, ga_g2, ga_be2, ga_m2, ga_v2,
                                          feats, (float*)d_out);
}